// Round 2
// baseline (415.818 us; speedup 1.0000x reference)
//
#include <hip/hip_runtime.h>

#define IN_F 4096
#define OUT_F 4096
#define BATCH 16384

// ws layout: ws[0..IN_F-1] = column sums of W, ws[IN_F] = bias sum.

// Kernel 1: column sums of W (row-major [OUT_F, IN_F]) + bias sum.
// grid = (4, 256), block = 256. Each thread owns one float4 column group;
// each blockIdx.y owns 16 rows. 1024 blocks -> ~4 blocks/CU for latency hiding.
__global__ __launch_bounds__(256) void colsum_kernel(
    const float* __restrict__ W, const float* __restrict__ bias,
    float* __restrict__ ws) {
  const int ROWS_PER_CHUNK = 16;
  int col4 = blockIdx.x * 256 + threadIdx.x;   // 0..1023 (float4 index)
  int row0 = blockIdx.y * ROWS_PER_CHUNK;
  const float4* W4 = (const float4*)W;

  float4 acc = make_float4(0.f, 0.f, 0.f, 0.f);
  #pragma unroll
  for (int r = 0; r < ROWS_PER_CHUNK; ++r) {
    float4 v = W4[(size_t)(row0 + r) * (IN_F / 4) + col4];
    acc.x += v.x; acc.y += v.y; acc.z += v.z; acc.w += v.w;
  }
  atomicAdd(&ws[col4 * 4 + 0], acc.x);
  atomicAdd(&ws[col4 * 4 + 1], acc.y);
  atomicAdd(&ws[col4 * 4 + 2], acc.z);
  atomicAdd(&ws[col4 * 4 + 3], acc.w);

  // Block (0,0) additionally reduces the bias vector.
  if (blockIdx.x == 0 && blockIdx.y == 0) {
    float b = 0.f;
    for (int i = threadIdx.x; i < OUT_F; i += 256) b += bias[i];
    #pragma unroll
    for (int off = 32; off > 0; off >>= 1) b += __shfl_down(b, off);
    if ((threadIdx.x & 63) == 0) atomicAdd(&ws[IN_F], b);
  }
}

// Kernel 2: out[row] = dot(x[row,:], colsum) + bias_sum.
// grid = 1024, block = 256 (4 waves), 4 rows per wave -> 16 rows per block.
// Each ds_read of the weight fragment is reused across 4 rows.
__global__ __launch_bounds__(256) void rowdot_kernel(
    const float* __restrict__ x, const float* __restrict__ ws,
    float* __restrict__ out) {
  __shared__ float4 sw[IN_F / 4];  // 16 KiB
  __shared__ float sbias;

  const float4* ws4 = (const float4*)ws;
  for (int i = threadIdx.x; i < IN_F / 4; i += 256) sw[i] = ws4[i];
  if (threadIdx.x == 0) sbias = ws[IN_F];
  __syncthreads();

  int wave = threadIdx.x >> 6;
  int lane = threadIdx.x & 63;
  int row0 = (blockIdx.x * 4 + wave) * 4;      // 4 consecutive rows per wave

  const int LD = IN_F / 4;                     // 1024 float4 per row
  const float4* x0 = (const float4*)(x + (size_t)row0 * IN_F);

  float a0 = 0.f, a1 = 0.f, a2 = 0.f, a3 = 0.f;
  #pragma unroll 4
  for (int it = 0; it < 16; ++it) {
    int o = it * 64 + lane;
    float4 wv = sw[o];
    float4 v0 = x0[o];
    float4 v1 = x0[o + LD];
    float4 v2 = x0[o + 2 * LD];
    float4 v3 = x0[o + 3 * LD];
    a0 += v0.x * wv.x + v0.y * wv.y + v0.z * wv.z + v0.w * wv.w;
    a1 += v1.x * wv.x + v1.y * wv.y + v1.z * wv.z + v1.w * wv.w;
    a2 += v2.x * wv.x + v2.y * wv.y + v2.z * wv.z + v2.w * wv.w;
    a3 += v3.x * wv.x + v3.y * wv.y + v3.z * wv.z + v3.w * wv.w;
  }
  #pragma unroll
  for (int off = 32; off > 0; off >>= 1) {
    a0 += __shfl_down(a0, off);
    a1 += __shfl_down(a1, off);
    a2 += __shfl_down(a2, off);
    a3 += __shfl_down(a3, off);
  }
  if (lane == 0) {
    float b = sbias;
    out[row0 + 0] = a0 + b;
    out[row0 + 1] = a1 + b;
    out[row0 + 2] = a2 + b;
    out[row0 + 3] = a3 + b;
  }
}

extern "C" void kernel_launch(void* const* d_in, const int* in_sizes, int n_in,
                              void* d_out, int out_size, void* d_ws, size_t ws_size,
                              hipStream_t stream) {
  const float* x    = (const float*)d_in[0];
  const float* W    = (const float*)d_in[1];
  const float* bias = (const float*)d_in[2];
  float* out = (float*)d_out;
  float* ws  = (float*)d_ws;

  // Zero the accumulator workspace (harness re-poisons d_ws before each call).
  hipMemsetAsync(ws, 0, (IN_F + 1) * sizeof(float), stream);

  dim3 g1(4, 256);
  colsum_kernel<<<g1, 256, 0, stream>>>(W, bias, ws);

  rowdot_kernel<<<BATCH / 16, 256, 0, stream>>>(x, ws, out);
}

// Round 3
// 406.169 us; speedup vs baseline: 1.0238x; 1.0238x over previous
//
#include <hip/hip_runtime.h>

#define IN_F 4096
#define OUT_F 4096
#define BATCH 16384

// ws layout: ws[0..IN_F-1] = column sums of W, ws[IN_F] = bias sum.

// Kernel 1: column sums of W (row-major [OUT_F, IN_F]) + bias sum.
// grid = (4, 128), block = 256. Each thread owns one float4 column group;
// each blockIdx.y owns 32 rows. 512 blocks = 2/CU, 8 waves/CU.
// Atomic contention: 128 adds per address over 4096 addresses (~2 us tail).
__global__ __launch_bounds__(256) void colsum_kernel(
    const float* __restrict__ W, const float* __restrict__ bias,
    float* __restrict__ ws) {
  const int ROWS_PER_CHUNK = 32;
  int col4 = blockIdx.x * 256 + threadIdx.x;   // 0..1023 (float4 index)
  int row0 = blockIdx.y * ROWS_PER_CHUNK;
  const float4* W4 = (const float4*)W;

  float4 acc = make_float4(0.f, 0.f, 0.f, 0.f);
  #pragma unroll 8
  for (int r = 0; r < ROWS_PER_CHUNK; ++r) {
    float4 v = W4[(size_t)(row0 + r) * (IN_F / 4) + col4];
    acc.x += v.x; acc.y += v.y; acc.z += v.z; acc.w += v.w;
  }
  atomicAdd(&ws[col4 * 4 + 0], acc.x);
  atomicAdd(&ws[col4 * 4 + 1], acc.y);
  atomicAdd(&ws[col4 * 4 + 2], acc.z);
  atomicAdd(&ws[col4 * 4 + 3], acc.w);

  // Block (0,0) additionally reduces the bias vector.
  if (blockIdx.x == 0 && blockIdx.y == 0) {
    float b = 0.f;
    for (int i = threadIdx.x; i < OUT_F; i += 256) b += bias[i];
    #pragma unroll
    for (int off = 32; off > 0; off >>= 1) b += __shfl_down(b, off);
    if ((threadIdx.x & 63) == 0) atomicAdd(&ws[IN_F], b);
  }
}

// Kernel 2: out[row] = dot(x[row,:], colsum) + bias_sum.
// grid = 2048, block = 256 (4 waves), 2 rows per wave -> 8 rows per block.
// 2048 blocks = 8 blocks/CU, 16 KiB LDS each -> 32 waves/CU (max occupancy).
__global__ __launch_bounds__(256) void rowdot_kernel(
    const float* __restrict__ x, const float* __restrict__ ws,
    float* __restrict__ out) {
  __shared__ float4 sw[IN_F / 4];  // 16 KiB
  __shared__ float sbias;

  const float4* ws4 = (const float4*)ws;
  for (int i = threadIdx.x; i < IN_F / 4; i += 256) sw[i] = ws4[i];
  if (threadIdx.x == 0) sbias = ws[IN_F];
  __syncthreads();

  int wave = threadIdx.x >> 6;
  int lane = threadIdx.x & 63;
  int row0 = blockIdx.x * 8 + wave * 2;        // 2 consecutive rows per wave

  const int LD = IN_F / 4;                     // 1024 float4 per row
  const float4* x0 = (const float4*)(x + (size_t)row0 * IN_F);

  float a0 = 0.f, a1 = 0.f;
  #pragma unroll 4
  for (int it = 0; it < 16; ++it) {
    int o = it * 64 + lane;
    float4 wv = sw[o];
    float4 v0 = x0[o];
    float4 v1 = x0[o + LD];
    a0 += v0.x * wv.x + v0.y * wv.y + v0.z * wv.z + v0.w * wv.w;
    a1 += v1.x * wv.x + v1.y * wv.y + v1.z * wv.z + v1.w * wv.w;
  }
  #pragma unroll
  for (int off = 32; off > 0; off >>= 1) {
    a0 += __shfl_down(a0, off);
    a1 += __shfl_down(a1, off);
  }
  if (lane == 0) {
    float b = sbias;
    out[row0 + 0] = a0 + b;
    out[row0 + 1] = a1 + b;
  }
}

extern "C" void kernel_launch(void* const* d_in, const int* in_sizes, int n_in,
                              void* d_out, int out_size, void* d_ws, size_t ws_size,
                              hipStream_t stream) {
  const float* x    = (const float*)d_in[0];
  const float* W    = (const float*)d_in[1];
  const float* bias = (const float*)d_in[2];
  float* out = (float*)d_out;
  float* ws  = (float*)d_ws;

  // Zero the accumulator workspace (harness re-poisons d_ws before each call).
  hipMemsetAsync(ws, 0, (IN_F + 1) * sizeof(float), stream);

  dim3 g1(4, 128);
  colsum_kernel<<<g1, 256, 0, stream>>>(W, bias, ws);

  rowdot_kernel<<<BATCH / 8, 256, 0, stream>>>(x, ws, out);
}